// Round 1
// baseline (130.613 us; speedup 1.0000x reference)
//
#include <hip/hip_runtime.h>
#include <float.h>

// Chamfer distance: gt_points [16384,3] f32, gen_points [16384,3] f32.
// out = mean(min_j |a_i-b_j|^2) + mean(min_i |a_i-b_j|^2), scalar f32.

#define NPTS 16384
constexpr int QPB    = 256;           // queries per block (= threads)
constexpr int SEGS   = 8;             // target-set segments
constexpr int SEGLEN = NPTS / SEGS;   // 2048 points, 24 KB LDS tile

// ws layout: uint32 min-slots [2][NPTS] (fp32 bit pattern; uint order == float
// order for non-negative values). Harness poisons ws/out with 0xAA each call,
// so init must run every launch.
__global__ void cd_init(unsigned* __restrict__ wsmin, float* __restrict__ out) {
    int i = blockIdx.x * blockDim.x + threadIdx.x;
    if (i < 2 * NPTS) wsmin[i] = 0x7F7FFFFFu;   // FLT_MAX bits
    if (i == 0) out[0] = 0.0f;
}

__global__ __launch_bounds__(QPB) void cd_min(const float* __restrict__ gt,
                                              const float* __restrict__ gen,
                                              unsigned* __restrict__ wsmin) {
    const int dir = blockIdx.z;                      // 0: gt->gen, 1: gen->gt
    const float* __restrict__ Q = dir ? gen : gt;    // queries
    const float* __restrict__ T = dir ? gt : gen;    // targets

    __shared__ float tile[SEGLEN * 3];

    // Cooperative float4 staging of this block's target segment (24 KB).
    {
        const float4* src = reinterpret_cast<const float4*>(T) +
                            (size_t)blockIdx.y * (SEGLEN * 3 / 4);
        float4* dst = reinterpret_cast<float4*>(tile);
        #pragma unroll
        for (int i = 0; i < (SEGLEN * 3 / 4) / QPB; ++i)   // 6 iters
            dst[i * QPB + threadIdx.x] = src[i * QPB + threadIdx.x];
    }

    const int q = blockIdx.x * QPB + threadIdx.x;
    const float qx = Q[3 * q + 0];
    const float qy = Q[3 * q + 1];
    const float qz = Q[3 * q + 2];

    __syncthreads();

    float m = FLT_MAX;
    const float4* t4 = reinterpret_cast<const float4*>(tile);

    // 4 points per iteration via 3 float4 LDS reads (broadcast: all lanes
    // read the same address -> no bank conflicts).
    for (int j = 0; j < SEGLEN / 4; ++j) {
        const float4 f0 = t4[3 * j + 0];
        const float4 f1 = t4[3 * j + 1];
        const float4 f2 = t4[3 * j + 2];

        float dx, dy, dz, d;
        dx = qx - f0.x; dy = qy - f0.y; dz = qz - f0.z;
        d = fmaf(dx, dx, fmaf(dy, dy, dz * dz)); m = fminf(m, d);
        dx = qx - f0.w; dy = qy - f1.x; dz = qz - f1.y;
        d = fmaf(dx, dx, fmaf(dy, dy, dz * dz)); m = fminf(m, d);
        dx = qx - f1.z; dy = qy - f1.w; dz = qz - f2.x;
        d = fmaf(dx, dx, fmaf(dy, dy, dz * dz)); m = fminf(m, d);
        dx = qx - f2.y; dy = qy - f2.z; dz = qz - f2.w;
        d = fmaf(dx, dx, fmaf(dy, dy, dz * dz)); m = fminf(m, d);
    }

    atomicMin(&wsmin[dir * NPTS + q], __float_as_uint(m));
}

__global__ __launch_bounds__(256) void cd_reduce(const unsigned* __restrict__ wsmin,
                                                 float* __restrict__ out) {
    const int i = blockIdx.x * 256 + threadIdx.x;
    float v = __uint_as_float(wsmin[i]);

    // wave64 shuffle reduction
    #pragma unroll
    for (int off = 32; off > 0; off >>= 1) v += __shfl_down(v, off, 64);

    __shared__ float wsum[4];
    const int lane = threadIdx.x & 63;
    const int wid  = threadIdx.x >> 6;
    if (lane == 0) wsum[wid] = v;
    __syncthreads();
    if (threadIdx.x == 0) {
        float s = wsum[0] + wsum[1] + wsum[2] + wsum[3];
        atomicAdd(out, s * (1.0f / (float)NPTS));
    }
}

extern "C" void kernel_launch(void* const* d_in, const int* in_sizes, int n_in,
                              void* d_out, int out_size, void* d_ws, size_t ws_size,
                              hipStream_t stream) {
    const float* gt  = (const float*)d_in[0];
    const float* gen = (const float*)d_in[1];
    unsigned* wsmin  = (unsigned*)d_ws;          // 2*16384*4 = 128 KB
    float* out       = (float*)d_out;

    cd_init<<<(2 * NPTS + 255) / 256, 256, 0, stream>>>(wsmin, out);

    dim3 grid(NPTS / QPB, SEGS, 2);              // 64 x 8 x 2 = 1024 blocks
    cd_min<<<grid, QPB, 0, stream>>>(gt, gen, wsmin);

    cd_reduce<<<(2 * NPTS) / 256, 256, 0, stream>>>(wsmin, out);
}